// Round 1
// baseline (400.589 us; speedup 1.0000x reference)
//
#include <hip/hip_runtime.h>
#include <hip/hip_bf16.h>
#include <stddef.h>

// ---------------- problem constants ----------------
#define NTOK   16384          // b*n = 4*4096
#define SEQN   4096
#define DIM    1024
#define K3     3072           // 3*DIM
#define HEADS  16
#define HD     64             // head dim

typedef __attribute__((ext_vector_type(8))) short short8;
typedef __attribute__((ext_vector_type(4))) float float4v;

static __device__ __forceinline__ unsigned short f32_to_bf16_bits(float f) {
    unsigned u = __float_as_uint(f);
    unsigned r = u + 0x7fffu + ((u >> 16) & 1u);   // RNE
    return (unsigned short)(r >> 16);
}
static __device__ __forceinline__ float bf16_bits_to_f32(unsigned short h) {
    return __uint_as_float(((unsigned)h) << 16);
}

// ---------------- prep: fp32 -> bf16 cast (vectorized) ----------------
__global__ void cvt_f32_bf16(const float4* __restrict__ in,
                             ushort4* __restrict__ out, int n4) {
    int i = blockIdx.x * blockDim.x + threadIdx.x;
    if (i < n4) {
        float4 v = in[i];
        ushort4 o;
        o.x = f32_to_bf16_bits(v.x);
        o.y = f32_to_bf16_bits(v.y);
        o.z = f32_to_bf16_bits(v.z);
        o.w = f32_to_bf16_bits(v.w);
        out[i] = o;
    }
}

// ---------------- prep: transpose K x N fp32 -> N x K bf16 ----------------
__global__ void transpose_cvt(const float* __restrict__ in,
                              unsigned short* __restrict__ out,
                              int K, int N) {
    __shared__ float t[32][33];
    int n0 = blockIdx.x * 32, k0 = blockIdx.y * 32;
    int tx = threadIdx.x, ty = threadIdx.y;     // block (32,8)
    #pragma unroll
    for (int r = ty; r < 32; r += 8)
        t[r][tx] = in[(size_t)(k0 + r) * N + n0 + tx];
    __syncthreads();
    #pragma unroll
    for (int r = ty; r < 32; r += 8)
        out[(size_t)(n0 + r) * K + k0 + tx] = f32_to_bf16_bits(t[tx][r]);
}

// ---------------- bf16 MFMA GEMM: C[M,N] = A[M,K] * Bt[N,K]^T ----------------
// 128x128 tile, BK=32, 256 threads = 4 waves, each wave a 64x64 quadrant
// of 4x4 16x16x32 MFMA tiles.  WITH_BIAS=1 -> fp32 out + bias, else bf16 out.
template<int WITH_BIAS>
__global__ __launch_bounds__(256) void gemm_bf16_128(
    const unsigned short* __restrict__ A,
    const unsigned short* __restrict__ Bt,
    void* __restrict__ Cout,
    const float* __restrict__ bias,
    int M, int N, int K)
{
    __shared__ unsigned short As[128][40];   // +8 pad: 2-way bank alias only
    __shared__ unsigned short Bs[128][40];

    const int tid  = threadIdx.x;
    const int wave = tid >> 6;
    const int lane = tid & 63;
    const int quad = lane >> 4;
    const int l16  = lane & 15;
    const int waveM = (wave & 1) * 64;
    const int waveN = (wave >> 1) * 64;
    const int rowBase = blockIdx.y * 128;
    const int colBase = blockIdx.x * 128;

    float4v acc[4][4];
    #pragma unroll
    for (int i = 0; i < 4; i++)
        #pragma unroll
        for (int j = 0; j < 4; j++)
            acc[i][j] = (float4v)0.0f;

    // staging: 512 16B-chunks per matrix / 256 threads = 2 each
    const int r0  = tid >> 2;            // rows 0..63, +64 for second chunk
    const int kc0 = (tid & 3) * 8;       // k offset within BK

    const unsigned short* Aptr = A  + (size_t)rowBase * K;
    const unsigned short* Bptr = Bt + (size_t)colBase * K;

    for (int k0 = 0; k0 < K; k0 += 32) {
        uint4 a0 = *(const uint4*)(Aptr + (size_t)r0 * K        + k0 + kc0);
        uint4 a1 = *(const uint4*)(Aptr + (size_t)(r0 + 64) * K + k0 + kc0);
        uint4 b0 = *(const uint4*)(Bptr + (size_t)r0 * K        + k0 + kc0);
        uint4 b1 = *(const uint4*)(Bptr + (size_t)(r0 + 64) * K + k0 + kc0);
        __syncthreads();
        *(uint4*)&As[r0][kc0]      = a0;
        *(uint4*)&As[r0 + 64][kc0] = a1;
        *(uint4*)&Bs[r0][kc0]      = b0;
        *(uint4*)&Bs[r0 + 64][kc0] = b1;
        __syncthreads();

        short8 af[4], bf[4];
        #pragma unroll
        for (int i = 0; i < 4; i++)
            af[i] = *(const short8*)&As[waveM + i * 16 + l16][quad * 8];
        #pragma unroll
        for (int j = 0; j < 4; j++)
            bf[j] = *(const short8*)&Bs[waveN + j * 16 + l16][quad * 8];

        #pragma unroll
        for (int i = 0; i < 4; i++)
            #pragma unroll
            for (int j = 0; j < 4; j++)
                acc[i][j] = __builtin_amdgcn_mfma_f32_16x16x32_bf16(
                                af[i], bf[j], acc[i][j], 0, 0, 0);
    }

    // epilogue: D[row][col], col = lane&15, row = quad*4 + r   (m89/m91)
    #pragma unroll
    for (int i = 0; i < 4; i++) {
        #pragma unroll
        for (int j = 0; j < 4; j++) {
            const int col = colBase + waveN + j * 16 + l16;
            #pragma unroll
            for (int r = 0; r < 4; r++) {
                const int row = rowBase + waveM + i * 16 + quad * 4 + r;
                float v = acc[i][j][r];
                if (WITH_BIAS) {
                    ((float*)Cout)[(size_t)row * N + col] = v + bias[col];
                } else {
                    ((unsigned short*)Cout)[(size_t)row * N + col] =
                        f32_to_bf16_bits(v);
                }
            }
        }
    }
}

// ---------------- per-token attention: rmsnorm+rope+QK^T+softmax+PV --------
__global__ __launch_bounds__(256) void attn_tok(
    const unsigned short* __restrict__ qkv,   // NTOK x 3072 bf16
    const float* __restrict__ fcos,           // 4096 x 32
    const float* __restrict__ fsin,
    const float* __restrict__ gq,             // 64
    const float* __restrict__ gk,
    unsigned short* __restrict__ outb)        // NTOK x 1024 bf16
{
    __shared__ float qs[16][68];
    __shared__ float ks[16][68];
    __shared__ float vs[16][68];
    __shared__ float Ps[16][17];

    const int tok = blockIdx.x;
    const int tid = threadIdx.x;
    const int n   = tok & (SEQN - 1);
    const int h   = tid >> 4;       // head (16) for rmsnorm / O-stage
    const int l   = tid & 15;       // 16 lanes per head
    const int d0  = l * 4;

    const unsigned short* base = qkv + (size_t)tok * K3;
    ushort4 qu = *(const ushort4*)(base + tid * 4);
    ushort4 ku = *(const ushort4*)(base + DIM + tid * 4);
    ushort4 vu = *(const ushort4*)(base + 2 * DIM + tid * 4);

    float qx = bf16_bits_to_f32(qu.x), qy = bf16_bits_to_f32(qu.y),
          qz = bf16_bits_to_f32(qu.z), qw = bf16_bits_to_f32(qu.w);
    float kx = bf16_bits_to_f32(ku.x), ky = bf16_bits_to_f32(ku.y),
          kz = bf16_bits_to_f32(ku.z), kw = bf16_bits_to_f32(ku.w);
    float vx = bf16_bits_to_f32(vu.x), vy = bf16_bits_to_f32(vu.y),
          vz = bf16_bits_to_f32(vu.z), vw = bf16_bits_to_f32(vu.w);

    *(float4*)&vs[h][d0] = make_float4(vx, vy, vz, vw);

    // RMSNorm over the 64-dim head: 16 lanes x 4 elems, intra-wave reduce
    float ssq = qx * qx + qy * qy + qz * qz + qw * qw;
    float ssk = kx * kx + ky * ky + kz * kz + kw * kw;
    #pragma unroll
    for (int o = 1; o < 16; o <<= 1) {
        ssq += __shfl_xor(ssq, o);
        ssk += __shfl_xor(ssk, o);
    }
    const float sq = 1.0f / (sqrtf(ssq) * 0.125f + 1e-6f);
    const float sk = 1.0f / (sqrtf(ssk) * 0.125f + 1e-6f);

    float4 g4q = *(const float4*)(gq + d0);
    float4 g4k = *(const float4*)(gk + d0);
    float qa = qx * sq * g4q.x, qb = qy * sq * g4q.y,
          qc = qz * sq * g4q.z, qd = qw * sq * g4q.w;
    float ka = kx * sk * g4k.x, kb = ky * sk * g4k.y,
          kc = kz * sk * g4k.z, kd = kw * sk * g4k.w;

    // RoPE: pairs (d0,d0+1),(d0+2,d0+3) -> freq indices l*2, l*2+1
    const int pi = n * (HD / 2) + l * 2;
    float c0 = fcos[pi],     s0 = fsin[pi];
    float c1 = fcos[pi + 1], s1 = fsin[pi + 1];
    *(float4*)&qs[h][d0] = make_float4(qa * c0 - qb * s0, qa * s0 + qb * c0,
                                       qc * c1 - qd * s1, qc * s1 + qd * c1);
    *(float4*)&ks[h][d0] = make_float4(ka * c0 - kb * s0, ka * s0 + kb * c0,
                                       kc * c1 - kd * s1, kc * s1 + kd * c1);
    __syncthreads();

    // S[h][g] = q_h . k_g * 1/8 ; thread (h, g=l)
    float s = 0.f;
    const float4* qrow = (const float4*)&qs[h][0];
    const float4* krow = (const float4*)&ks[l][0];
    #pragma unroll
    for (int t = 0; t < 16; t++) {
        float4 a = qrow[t], b = krow[t];
        s += a.x * b.x + a.y * b.y + a.z * b.z + a.w * b.w;
    }
    s *= 0.125f;

    // softmax over g (the aligned 16-lane group)
    float m = s;
    #pragma unroll
    for (int o = 1; o < 16; o <<= 1) m = fmaxf(m, __shfl_xor(m, o));
    float e = __expf(s - m);
    float sum = e;
    #pragma unroll
    for (int o = 1; o < 16; o <<= 1) sum += __shfl_xor(sum, o);
    Ps[h][l] = e / sum;
    __syncthreads();

    // O[h][d0..d0+3] = sum_g P[h][g] * V[g][d]
    float ox = 0.f, oy = 0.f, oz = 0.f, ow = 0.f;
    #pragma unroll
    for (int g = 0; g < 16; g++) {
        float p = Ps[h][g];
        float4 vv = *(const float4*)&vs[g][d0];
        ox += p * vv.x; oy += p * vv.y; oz += p * vv.z; ow += p * vv.w;
    }
    ushort4 ob;
    ob.x = f32_to_bf16_bits(ox);
    ob.y = f32_to_bf16_bits(oy);
    ob.z = f32_to_bf16_bits(oz);
    ob.w = f32_to_bf16_bits(ow);
    *(ushort4*)(outb + (size_t)tok * DIM + tid * 4) = ob;
}

// ---------------- launch ----------------
extern "C" void kernel_launch(void* const* d_in, const int* in_sizes, int n_in,
                              void* d_out, int out_size, void* d_ws, size_t ws_size,
                              hipStream_t stream) {
    const float* x      = (const float*)d_in[0];   // 16384 x 1024
    const float* fcos   = (const float*)d_in[1];   // 4096 x 32
    const float* fsin   = (const float*)d_in[2];
    const float* w_qkv  = (const float*)d_in[3];   // 1024 x 3072
    const float* g_q    = (const float*)d_in[4];
    const float* g_k    = (const float*)d_in[5];
    const float* w_proj = (const float*)d_in[6];   // 1024 x 1024
    const float* b_proj = (const float*)d_in[7];
    float* out = (float*)d_out;

    char* ws = (char*)d_ws;
    // workspace layout (bytes)
    unsigned short* xb      = (unsigned short*)(ws);                       // 33,554,432
    unsigned short* wqkvT   = (unsigned short*)(ws + 33554432);            //  6,291,456
    unsigned short* wprojT  = (unsigned short*)(ws + 39845888);            //  2,097,152
    unsigned short* qkv     = (unsigned short*)(ws + 41943040);            // 100,663,296
    unsigned short* attnout = (unsigned short*)(ws + 142606336);           // 33,554,432
    (void)ws_size; (void)in_sizes; (void)n_in; (void)out_size;

    // 1. casts / transposes
    {
        int n4 = (NTOK * DIM) / 4;   // 4,194,304
        cvt_f32_bf16<<<(n4 + 255) / 256, 256, 0, stream>>>(
            (const float4*)x, (ushort4*)xb, n4);
        transpose_cvt<<<dim3(K3 / 32, DIM / 32), dim3(32, 8), 0, stream>>>(
            w_qkv, wqkvT, DIM, K3);
        transpose_cvt<<<dim3(DIM / 32, DIM / 32), dim3(32, 8), 0, stream>>>(
            w_proj, wprojT, DIM, DIM);
    }
    // 2. qkv = x @ w_qkv   (bf16 out)
    gemm_bf16_128<0><<<dim3(K3 / 128, NTOK / 128), 256, 0, stream>>>(
        xb, wqkvT, (void*)qkv, nullptr, NTOK, K3, DIM);
    // 3. per-token attention
    attn_tok<<<NTOK, 256, 0, stream>>>(qkv, fcos, fsin, g_q, g_k, attnout);
    // 4. out = attn @ w_proj + b   (fp32 out)
    gemm_bf16_128<1><<<dim3(DIM / 128, NTOK / 128), 256, 0, stream>>>(
        attnout, wprojT, (void*)out, b_proj, NTOK, DIM, DIM);
}

// Round 2
// 381.129 us; speedup vs baseline: 1.0511x; 1.0511x over previous
//
#include <hip/hip_runtime.h>
#include <hip/hip_bf16.h>
#include <stddef.h>

// ---------------- problem constants ----------------
#define NTOK   16384          // b*n = 4*4096
#define SEQN   4096
#define DIM    1024
#define K3     3072           // 3*DIM
#define HEADS  16
#define HD     64             // head dim

typedef __attribute__((ext_vector_type(8))) short short8;
typedef __attribute__((ext_vector_type(4))) float float4v;

static __device__ __forceinline__ unsigned short f32_to_bf16_bits(float f) {
    unsigned u = __float_as_uint(f);
    unsigned r = u + 0x7fffu + ((u >> 16) & 1u);   // RNE
    return (unsigned short)(r >> 16);
}
static __device__ __forceinline__ float bf16_bits_to_f32(unsigned short h) {
    return __uint_as_float(((unsigned)h) << 16);
}

// async global->LDS DMA, 16B per lane, LDS dst = uniform base + lane*16
typedef const void __attribute__((address_space(1)))* gas_ptr;
typedef void __attribute__((address_space(3)))* las_ptr;
static __device__ __forceinline__ void gload_lds16(const unsigned short* g,
                                                   unsigned short* l) {
    __builtin_amdgcn_global_load_lds((gas_ptr)g, (las_ptr)l, 16, 0, 0);
}

// ---------------- prep: fp32 -> bf16 cast (vectorized) ----------------
__global__ void cvt_f32_bf16(const float4* __restrict__ in,
                             ushort4* __restrict__ out, int n4) {
    int i = blockIdx.x * blockDim.x + threadIdx.x;
    if (i < n4) {
        float4 v = in[i];
        ushort4 o;
        o.x = f32_to_bf16_bits(v.x);
        o.y = f32_to_bf16_bits(v.y);
        o.z = f32_to_bf16_bits(v.z);
        o.w = f32_to_bf16_bits(v.w);
        out[i] = o;
    }
}

// ---------------- prep: transpose K x N fp32 -> N x K bf16 ----------------
__global__ void transpose_cvt(const float* __restrict__ in,
                              unsigned short* __restrict__ out,
                              int K, int N) {
    __shared__ float t[32][33];
    int n0 = blockIdx.x * 32, k0 = blockIdx.y * 32;
    int tx = threadIdx.x, ty = threadIdx.y;     // block (32,8)
    #pragma unroll
    for (int r = ty; r < 32; r += 8)
        t[r][tx] = in[(size_t)(k0 + r) * N + n0 + tx];
    __syncthreads();
    #pragma unroll
    for (int r = ty; r < 32; r += 8)
        out[(size_t)(n0 + r) * K + k0 + tx] = f32_to_bf16_bits(t[tx][r]);
}

// ---------------- bf16 MFMA GEMM: C[M,N] = A[M,K] * Bt[N,K]^T ----------------
// m97 structure: 128x128 tile, BK=32, 256 threads = 4 waves, each wave a
// 64x64 quadrant of 4x4 16x16x32 MFMA tiles; staging via global_load_lds
// dwordx4 (UNPADDED LDS: DMA writes base + lane*16 — padding would corrupt).
template<int WITH_BIAS>
__global__ __launch_bounds__(256) void gemm_bf16_128(
    const unsigned short* __restrict__ A,
    const unsigned short* __restrict__ Bt,
    void* __restrict__ Cout,
    const float* __restrict__ bias,
    int M, int N, int K)
{
    __shared__ unsigned short As[128][32];   // 64 B/row, contiguous for DMA
    __shared__ unsigned short Bs[128][32];

    const int tid  = threadIdx.x;
    const int wave = tid >> 6;
    const int lane = tid & 63;
    const int quad = lane >> 4;
    const int l16  = lane & 15;
    const int waveM = (wave & 1) * 64;
    const int waveN = (wave >> 1) * 64;
    const int rowBase = blockIdx.y * 128;
    const int colBase = blockIdx.x * 128;

    float4v acc[4][4];
    #pragma unroll
    for (int i = 0; i < 4; i++)
        #pragma unroll
        for (int j = 0; j < 4; j++)
            acc[i][j] = (float4v)0.0f;

    // staging geometry: wave w DMAs rows [w*32, w*32+32) of A and B,
    // two 16-row issues each; lane covers (row = base + lane>>2,
    // col = (lane&3)*8 shorts) -> LDS offset lane*16 from the uniform base.
    const int lrow = lane >> 2;
    const int lcol = (lane & 3) * 8;
    const unsigned short* gA = A  + (size_t)(rowBase + wave * 32 + lrow) * K + lcol;
    const unsigned short* gB = Bt + (size_t)(colBase + wave * 32 + lrow) * K + lcol;
    unsigned short* lA0 = &As[wave * 32][0];
    unsigned short* lA1 = &As[wave * 32 + 16][0];
    unsigned short* lB0 = &Bs[wave * 32][0];
    unsigned short* lB1 = &Bs[wave * 32 + 16][0];
    const size_t k16 = (size_t)16 * K;

    for (int k0 = 0; k0 < K; k0 += 32) {
        __syncthreads();                       // LDS safe to overwrite
        gload_lds16(gA + k0,        lA0);
        gload_lds16(gA + k0 + k16,  lA1);
        gload_lds16(gB + k0,        lB0);
        gload_lds16(gB + k0 + k16,  lB1);
        __syncthreads();                       // drains vmcnt -> data ready

        short8 af[4], bf[4];
        #pragma unroll
        for (int i = 0; i < 4; i++)
            af[i] = *(const short8*)&As[waveM + i * 16 + l16][quad * 8];
        #pragma unroll
        for (int j = 0; j < 4; j++)
            bf[j] = *(const short8*)&Bs[waveN + j * 16 + l16][quad * 8];

        #pragma unroll
        for (int i = 0; i < 4; i++)
            #pragma unroll
            for (int j = 0; j < 4; j++)
                acc[i][j] = __builtin_amdgcn_mfma_f32_16x16x32_bf16(
                                af[i], bf[j], acc[i][j], 0, 0, 0);
    }

    // epilogue: D[row][col], col = lane&15, row = quad*4 + r   (m89/m91)
    #pragma unroll
    for (int i = 0; i < 4; i++) {
        #pragma unroll
        for (int j = 0; j < 4; j++) {
            const int col = colBase + waveN + j * 16 + l16;
            #pragma unroll
            for (int r = 0; r < 4; r++) {
                const int row = rowBase + waveM + i * 16 + quad * 4 + r;
                float v = acc[i][j][r];
                if (WITH_BIAS) {
                    ((float*)Cout)[(size_t)row * N + col] = v + bias[col];
                } else {
                    ((unsigned short*)Cout)[(size_t)row * N + col] =
                        f32_to_bf16_bits(v);
                }
            }
        }
    }
}

// ---------------- per-token attention: rmsnorm+rope+QK^T+softmax+PV --------
__global__ __launch_bounds__(256) void attn_tok(
    const unsigned short* __restrict__ qkv,   // NTOK x 3072 bf16
    const float* __restrict__ fcos,           // 4096 x 32
    const float* __restrict__ fsin,
    const float* __restrict__ gq,             // 64
    const float* __restrict__ gk,
    unsigned short* __restrict__ outb)        // NTOK x 1024 bf16
{
    __shared__ float qs[16][68];
    __shared__ float ks[16][68];
    __shared__ float vs[16][68];
    __shared__ float Ps[16][17];

    const int tok = blockIdx.x;
    const int tid = threadIdx.x;
    const int n   = tok & (SEQN - 1);
    const int h   = tid >> 4;       // head (16) for rmsnorm / O-stage
    const int l   = tid & 15;       // 16 lanes per head
    const int d0  = l * 4;

    const unsigned short* base = qkv + (size_t)tok * K3;
    ushort4 qu = *(const ushort4*)(base + tid * 4);
    ushort4 ku = *(const ushort4*)(base + DIM + tid * 4);
    ushort4 vu = *(const ushort4*)(base + 2 * DIM + tid * 4);

    float qx = bf16_bits_to_f32(qu.x), qy = bf16_bits_to_f32(qu.y),
          qz = bf16_bits_to_f32(qu.z), qw = bf16_bits_to_f32(qu.w);
    float kx = bf16_bits_to_f32(ku.x), ky = bf16_bits_to_f32(ku.y),
          kz = bf16_bits_to_f32(ku.z), kw = bf16_bits_to_f32(ku.w);
    float vx = bf16_bits_to_f32(vu.x), vy = bf16_bits_to_f32(vu.y),
          vz = bf16_bits_to_f32(vu.z), vw = bf16_bits_to_f32(vu.w);

    *(float4*)&vs[h][d0] = make_float4(vx, vy, vz, vw);

    // RMSNorm over the 64-dim head: 16 lanes x 4 elems, intra-wave reduce
    float ssq = qx * qx + qy * qy + qz * qz + qw * qw;
    float ssk = kx * kx + ky * ky + kz * kz + kw * kw;
    #pragma unroll
    for (int o = 1; o < 16; o <<= 1) {
        ssq += __shfl_xor(ssq, o);
        ssk += __shfl_xor(ssk, o);
    }
    const float sq = 1.0f / (sqrtf(ssq) * 0.125f + 1e-6f);
    const float sk = 1.0f / (sqrtf(ssk) * 0.125f + 1e-6f);

    float4 g4q = *(const float4*)(gq + d0);
    float4 g4k = *(const float4*)(gk + d0);
    float qa = qx * sq * g4q.x, qb = qy * sq * g4q.y,
          qc = qz * sq * g4q.z, qd = qw * sq * g4q.w;
    float ka = kx * sk * g4k.x, kb = ky * sk * g4k.y,
          kc = kz * sk * g4k.z, kd = kw * sk * g4k.w;

    // RoPE: pairs (d0,d0+1),(d0+2,d0+3) -> freq indices l*2, l*2+1
    const int pi = n * (HD / 2) + l * 2;
    float c0 = fcos[pi],     s0 = fsin[pi];
    float c1 = fcos[pi + 1], s1 = fsin[pi + 1];
    *(float4*)&qs[h][d0] = make_float4(qa * c0 - qb * s0, qa * s0 + qb * c0,
                                       qc * c1 - qd * s1, qc * s1 + qd * c1);
    *(float4*)&ks[h][d0] = make_float4(ka * c0 - kb * s0, ka * s0 + kb * c0,
                                       kc * c1 - kd * s1, kc * s1 + kd * c1);
    __syncthreads();

    // S[h][g] = q_h . k_g * 1/8 ; thread (h, g=l)
    float s = 0.f;
    const float4* qrow = (const float4*)&qs[h][0];
    const float4* krow = (const float4*)&ks[l][0];
    #pragma unroll
    for (int t = 0; t < 16; t++) {
        float4 a = qrow[t], b = krow[t];
        s += a.x * b.x + a.y * b.y + a.z * b.z + a.w * b.w;
    }
    s *= 0.125f;

    // softmax over g (the aligned 16-lane group)
    float m = s;
    #pragma unroll
    for (int o = 1; o < 16; o <<= 1) m = fmaxf(m, __shfl_xor(m, o));
    float e = __expf(s - m);
    float sum = e;
    #pragma unroll
    for (int o = 1; o < 16; o <<= 1) sum += __shfl_xor(sum, o);
    Ps[h][l] = e / sum;
    __syncthreads();

    // O[h][d0..d0+3] = sum_g P[h][g] * V[g][d]
    float ox = 0.f, oy = 0.f, oz = 0.f, ow = 0.f;
    #pragma unroll
    for (int g = 0; g < 16; g++) {
        float p = Ps[h][g];
        float4 vv = *(const float4*)&vs[g][d0];
        ox += p * vv.x; oy += p * vv.y; oz += p * vv.z; ow += p * vv.w;
    }
    ushort4 ob;
    ob.x = f32_to_bf16_bits(ox);
    ob.y = f32_to_bf16_bits(oy);
    ob.z = f32_to_bf16_bits(oz);
    ob.w = f32_to_bf16_bits(ow);
    *(ushort4*)(outb + (size_t)tok * DIM + tid * 4) = ob;
}

// ---------------- launch ----------------
extern "C" void kernel_launch(void* const* d_in, const int* in_sizes, int n_in,
                              void* d_out, int out_size, void* d_ws, size_t ws_size,
                              hipStream_t stream) {
    const float* x      = (const float*)d_in[0];   // 16384 x 1024
    const float* fcos   = (const float*)d_in[1];   // 4096 x 32
    const float* fsin   = (const float*)d_in[2];
    const float* w_qkv  = (const float*)d_in[3];   // 1024 x 3072
    const float* g_q    = (const float*)d_in[4];
    const float* g_k    = (const float*)d_in[5];
    const float* w_proj = (const float*)d_in[6];   // 1024 x 1024
    const float* b_proj = (const float*)d_in[7];
    float* out = (float*)d_out;

    char* ws = (char*)d_ws;
    // workspace layout (bytes)
    unsigned short* xb      = (unsigned short*)(ws);                       // 33,554,432
    unsigned short* wqkvT   = (unsigned short*)(ws + 33554432);            //  6,291,456
    unsigned short* wprojT  = (unsigned short*)(ws + 39845888);            //  2,097,152
    unsigned short* qkv     = (unsigned short*)(ws + 41943040);            // 100,663,296
    unsigned short* attnout = (unsigned short*)(ws + 142606336);           // 33,554,432
    (void)ws_size; (void)in_sizes; (void)n_in; (void)out_size;

    // 1. casts / transposes
    {
        int n4 = (NTOK * DIM) / 4;   // 4,194,304
        cvt_f32_bf16<<<(n4 + 255) / 256, 256, 0, stream>>>(
            (const float4*)x, (ushort4*)xb, n4);
        transpose_cvt<<<dim3(K3 / 32, DIM / 32), dim3(32, 8), 0, stream>>>(
            w_qkv, wqkvT, DIM, K3);
        transpose_cvt<<<dim3(DIM / 32, DIM / 32), dim3(32, 8), 0, stream>>>(
            w_proj, wprojT, DIM, DIM);
    }
    // 2. qkv = x @ w_qkv   (bf16 out)
    gemm_bf16_128<0><<<dim3(K3 / 128, NTOK / 128), 256, 0, stream>>>(
        xb, wqkvT, (void*)qkv, nullptr, NTOK, K3, DIM);
    // 3. per-token attention
    attn_tok<<<NTOK, 256, 0, stream>>>(qkv, fcos, fsin, g_q, g_k, attnout);
    // 4. out = attn @ w_proj + b   (fp32 out)
    gemm_bf16_128<1><<<dim3(DIM / 128, NTOK / 128), 256, 0, stream>>>(
        attnout, wprojT, (void*)out, b_proj, NTOK, DIM, DIM);
}

// Round 3
// 381.022 us; speedup vs baseline: 1.0514x; 1.0003x over previous
//
#include <hip/hip_runtime.h>
#include <hip/hip_bf16.h>
#include <stddef.h>

// ---------------- problem constants ----------------
#define NTOK   16384          // b*n = 4*4096
#define SEQN   4096
#define DIM    1024
#define K3     3072           // 3*DIM
#define HEADS  16
#define HD     64             // head dim

typedef __attribute__((ext_vector_type(8))) short short8;
typedef __attribute__((ext_vector_type(4))) float float4v;

static __device__ __forceinline__ unsigned short f32_to_bf16_bits(float f) {
    unsigned u = __float_as_uint(f);
    unsigned r = u + 0x7fffu + ((u >> 16) & 1u);   // RNE
    return (unsigned short)(r >> 16);
}
static __device__ __forceinline__ unsigned pack_bf16x2(float lo, float hi) {
    return (unsigned)f32_to_bf16_bits(lo) | ((unsigned)f32_to_bf16_bits(hi) << 16);
}
static __device__ __forceinline__ void unpack_bf16x8(uint4 u, float* f) {
    f[0] = __uint_as_float(u.x << 16); f[1] = __uint_as_float(u.x & 0xffff0000u);
    f[2] = __uint_as_float(u.y << 16); f[3] = __uint_as_float(u.y & 0xffff0000u);
    f[4] = __uint_as_float(u.z << 16); f[5] = __uint_as_float(u.z & 0xffff0000u);
    f[6] = __uint_as_float(u.w << 16); f[7] = __uint_as_float(u.w & 0xffff0000u);
}

// async global->LDS DMA, 16B per lane, LDS dst = uniform base + lane*16
typedef const void __attribute__((address_space(1)))* gas_ptr;
typedef void __attribute__((address_space(3)))* las_ptr;
static __device__ __forceinline__ void gload_lds16(const unsigned short* g,
                                                   unsigned short* l) {
    __builtin_amdgcn_global_load_lds((gas_ptr)g, (las_ptr)l, 16, 0, 0);
}

// ---------------- prep: fp32 -> bf16 cast (vectorized) ----------------
__global__ void cvt_f32_bf16(const float4* __restrict__ in,
                             ushort4* __restrict__ out, int n4) {
    int i = blockIdx.x * blockDim.x + threadIdx.x;
    if (i < n4) {
        float4 v = in[i];
        ushort4 o;
        o.x = f32_to_bf16_bits(v.x);
        o.y = f32_to_bf16_bits(v.y);
        o.z = f32_to_bf16_bits(v.z);
        o.w = f32_to_bf16_bits(v.w);
        out[i] = o;
    }
}

// ---------------- prep: transpose K x N fp32 -> N x K bf16 ----------------
__global__ void transpose_cvt(const float* __restrict__ in,
                              unsigned short* __restrict__ out,
                              int K, int N) {
    __shared__ float t[32][33];
    int n0 = blockIdx.x * 32, k0 = blockIdx.y * 32;
    int tx = threadIdx.x, ty = threadIdx.y;     // block (32,8)
    #pragma unroll
    for (int r = ty; r < 32; r += 8)
        t[r][tx] = in[(size_t)(k0 + r) * N + n0 + tx];
    __syncthreads();
    #pragma unroll
    for (int r = ty; r < 32; r += 8)
        out[(size_t)(n0 + r) * K + k0 + tx] = f32_to_bf16_bits(t[tx][r]);
}

// ---------------- bf16 MFMA GEMM: C[M,N] = A[M,K] * Bt[N,K]^T ----------------
// m97 structure: 128x128 tile, BK=32, 256 threads = 4 waves, each wave a
// 64x64 quadrant of 4x4 16x16x32 MFMA tiles; staging via global_load_lds
// dwordx4 (UNPADDED LDS: DMA writes base + lane*16 — padding would corrupt).
template<int WITH_BIAS>
__global__ __launch_bounds__(256) void gemm_bf16_128(
    const unsigned short* __restrict__ A,
    const unsigned short* __restrict__ Bt,
    void* __restrict__ Cout,
    const float* __restrict__ bias,
    int M, int N, int K)
{
    __shared__ unsigned short As[128][32];   // 64 B/row, contiguous for DMA
    __shared__ unsigned short Bs[128][32];

    const int tid  = threadIdx.x;
    const int wave = tid >> 6;
    const int lane = tid & 63;
    const int quad = lane >> 4;
    const int l16  = lane & 15;
    const int waveM = (wave & 1) * 64;
    const int waveN = (wave >> 1) * 64;
    const int rowBase = blockIdx.y * 128;
    const int colBase = blockIdx.x * 128;

    float4v acc[4][4];
    #pragma unroll
    for (int i = 0; i < 4; i++)
        #pragma unroll
        for (int j = 0; j < 4; j++)
            acc[i][j] = (float4v)0.0f;

    // staging geometry: wave w DMAs rows [w*32, w*32+32) of A and B,
    // two 16-row issues each; lane covers (row = base + lane>>2,
    // col = (lane&3)*8 shorts) -> LDS offset lane*16 from the uniform base.
    const int lrow = lane >> 2;
    const int lcol = (lane & 3) * 8;
    const unsigned short* gA = A  + (size_t)(rowBase + wave * 32 + lrow) * K + lcol;
    const unsigned short* gB = Bt + (size_t)(colBase + wave * 32 + lrow) * K + lcol;
    unsigned short* lA0 = &As[wave * 32][0];
    unsigned short* lA1 = &As[wave * 32 + 16][0];
    unsigned short* lB0 = &Bs[wave * 32][0];
    unsigned short* lB1 = &Bs[wave * 32 + 16][0];
    const size_t k16 = (size_t)16 * K;

    for (int k0 = 0; k0 < K; k0 += 32) {
        __syncthreads();                       // LDS safe to overwrite
        gload_lds16(gA + k0,        lA0);
        gload_lds16(gA + k0 + k16,  lA1);
        gload_lds16(gB + k0,        lB0);
        gload_lds16(gB + k0 + k16,  lB1);
        __syncthreads();                       // drains vmcnt -> data ready

        short8 af[4], bf[4];
        #pragma unroll
        for (int i = 0; i < 4; i++)
            af[i] = *(const short8*)&As[waveM + i * 16 + l16][quad * 8];
        #pragma unroll
        for (int j = 0; j < 4; j++)
            bf[j] = *(const short8*)&Bs[waveN + j * 16 + l16][quad * 8];

        #pragma unroll
        for (int i = 0; i < 4; i++)
            #pragma unroll
            for (int j = 0; j < 4; j++)
                acc[i][j] = __builtin_amdgcn_mfma_f32_16x16x32_bf16(
                                af[i], bf[j], acc[i][j], 0, 0, 0);
    }

    // epilogue: D[row][col], col = lane&15, row = quad*4 + r   (m89/m91)
    #pragma unroll
    for (int i = 0; i < 4; i++) {
        #pragma unroll
        for (int j = 0; j < 4; j++) {
            const int col = colBase + waveN + j * 16 + l16;
            #pragma unroll
            for (int r = 0; r < 4; r++) {
                const int row = rowBase + waveM + i * 16 + quad * 4 + r;
                float v = acc[i][j][r];
                if (WITH_BIAS) {
                    ((float*)Cout)[(size_t)row * N + col] = v + bias[col];
                } else {
                    ((unsigned short*)Cout)[(size_t)row * N + col] =
                        f32_to_bf16_bits(v);
                }
            }
        }
    }
}

// ---------------- per-token attention: wave-per-token, barrier-free --------
// 4 waves/block, 1 token/wave. Lane l: head h=l&15, dim-slice p=l>>4
// ([16p,16p+16)). RMSNorm+RoPE in-register; roped K and raw V staged in a
// per-wave fp32 LDS tile; S and P.V read them as 4-address broadcast b128s.
// Softmax is lane-local (each lane holds the full 16-wide S row after the
// cross-p shuffle reduce). No __syncthreads.
__global__ __launch_bounds__(256) void attn_tok(
    const unsigned short* __restrict__ qkv,   // NTOK x 3072 bf16
    const float* __restrict__ fcos,           // 4096 x 32
    const float* __restrict__ fsin,
    const float* __restrict__ gq,             // 64
    const float* __restrict__ gk,
    unsigned short* __restrict__ outb)        // NTOK x 1024 bf16
{
    __shared__ float kl[4][16][68];   // [wave][g][dim] stride 68: 2-way alias
    __shared__ float vl[4][16][68];

    const int tid  = threadIdx.x;
    const int wv   = tid >> 6;
    const int lane = tid & 63;
    const int h    = lane & 15;
    const int p    = lane >> 4;
    const int tok  = blockIdx.x * 4 + wv;
    const int n    = tok & (SEQN - 1);

    const unsigned short* base = qkv + (size_t)tok * K3 + h * 64 + p * 16;
    uint4 qr0 = *(const uint4*)(base);
    uint4 qr1 = *(const uint4*)(base + 8);
    uint4 kr0 = *(const uint4*)(base + DIM);
    uint4 kr1 = *(const uint4*)(base + DIM + 8);
    uint4 vr0 = *(const uint4*)(base + 2 * DIM);
    uint4 vr1 = *(const uint4*)(base + 2 * DIM + 8);

    float q[16], k[16], v[16];
    unpack_bf16x8(qr0, q); unpack_bf16x8(qr1, q + 8);
    unpack_bf16x8(kr0, k); unpack_bf16x8(kr1, k + 8);
    unpack_bf16x8(vr0, v); unpack_bf16x8(vr1, v + 8);

    // RMSNorm over the 64-dim head (reduce across the 4 p-slices)
    float ssq = 0.f, ssk = 0.f;
    #pragma unroll
    for (int i = 0; i < 16; i++) { ssq += q[i] * q[i]; ssk += k[i] * k[i]; }
    ssq += __shfl_xor(ssq, 16); ssq += __shfl_xor(ssq, 32);
    ssk += __shfl_xor(ssk, 16); ssk += __shfl_xor(ssk, 32);
    const float sq = 1.0f / (sqrtf(ssq) * 0.125f + 1e-6f);
    const float sk = 1.0f / (sqrtf(ssk) * 0.125f + 1e-6f);

    #pragma unroll
    for (int c = 0; c < 4; c++) {
        float4 gg = *(const float4*)(gq + p * 16 + c * 4);
        float4 gh = *(const float4*)(gk + p * 16 + c * 4);
        q[c*4+0] *= sq * gg.x; q[c*4+1] *= sq * gg.y;
        q[c*4+2] *= sq * gg.z; q[c*4+3] *= sq * gg.w;
        k[c*4+0] *= sk * gh.x; k[c*4+1] *= sk * gh.y;
        k[c*4+2] *= sk * gh.z; k[c*4+3] *= sk * gh.w;
    }

    // RoPE: local pair j -> global pair index 8p+j
    {
        const float* cb = fcos + n * 32 + p * 8;
        const float* sb = fsin + n * 32 + p * 8;
        float4 c0 = *(const float4*)cb, c1 = *(const float4*)(cb + 4);
        float4 s0 = *(const float4*)sb, s1 = *(const float4*)(sb + 4);
        float cs[8] = {c0.x,c0.y,c0.z,c0.w,c1.x,c1.y,c1.z,c1.w};
        float sn[8] = {s0.x,s0.y,s0.z,s0.w,s1.x,s1.y,s1.z,s1.w};
        #pragma unroll
        for (int j = 0; j < 8; j++) {
            float re = q[2*j], im = q[2*j+1];
            q[2*j]   = re * cs[j] - im * sn[j];
            q[2*j+1] = re * sn[j] + im * cs[j];
            re = k[2*j]; im = k[2*j+1];
            k[2*j]   = re * cs[j] - im * sn[j];
            k[2*j+1] = re * sn[j] + im * cs[j];
        }
    }

    // stage roped K and raw V into the per-wave LDS tile
    {
        float* krow = &kl[wv][h][p * 16];
        float* vrow = &vl[wv][h][p * 16];
        #pragma unroll
        for (int c = 0; c < 4; c++) {
            *(float4*)(krow + c*4) = make_float4(k[c*4], k[c*4+1], k[c*4+2], k[c*4+3]);
            *(float4*)(vrow + c*4) = make_float4(v[c*4], v[c*4+1], v[c*4+2], v[c*4+3]);
        }
    }

    // S[h][g] partial over this lane's 16 dims, then reduce across p
    float s[16];
    #pragma unroll
    for (int g = 0; g < 16; g++) {
        const float* kg = &kl[wv][g][p * 16];
        float4 a0 = *(const float4*)(kg);
        float4 a1 = *(const float4*)(kg + 4);
        float4 a2 = *(const float4*)(kg + 8);
        float4 a3 = *(const float4*)(kg + 12);
        s[g] = q[0]*a0.x + q[1]*a0.y + q[2]*a0.z + q[3]*a0.w
             + q[4]*a1.x + q[5]*a1.y + q[6]*a1.z + q[7]*a1.w
             + q[8]*a2.x + q[9]*a2.y + q[10]*a2.z + q[11]*a2.w
             + q[12]*a3.x + q[13]*a3.y + q[14]*a3.z + q[15]*a3.w;
    }
    #pragma unroll
    for (int g = 0; g < 16; g++) {
        s[g] += __shfl_xor(s[g], 16);
        s[g] += __shfl_xor(s[g], 32);
        s[g] *= 0.125f;
    }

    // lane-local softmax over g
    float m = s[0];
    #pragma unroll
    for (int g = 1; g < 16; g++) m = fmaxf(m, s[g]);
    float sum = 0.f;
    #pragma unroll
    for (int g = 0; g < 16; g++) { s[g] = __expf(s[g] - m); sum += s[g]; }
    const float inv = 1.0f / sum;

    // O[h][slice p] = sum_g P[g] * V[g][slice p]
    float o[16];
    #pragma unroll
    for (int i = 0; i < 16; i++) o[i] = 0.f;
    #pragma unroll
    for (int g = 0; g < 16; g++) {
        const float pg = s[g] * inv;
        const float* vg = &vl[wv][g][p * 16];
        float4 b0 = *(const float4*)(vg);
        float4 b1 = *(const float4*)(vg + 4);
        float4 b2 = *(const float4*)(vg + 8);
        float4 b3 = *(const float4*)(vg + 12);
        o[0]  += pg * b0.x; o[1]  += pg * b0.y; o[2]  += pg * b0.z; o[3]  += pg * b0.w;
        o[4]  += pg * b1.x; o[5]  += pg * b1.y; o[6]  += pg * b1.z; o[7]  += pg * b1.w;
        o[8]  += pg * b2.x; o[9]  += pg * b2.y; o[10] += pg * b2.z; o[11] += pg * b2.w;
        o[12] += pg * b3.x; o[13] += pg * b3.y; o[14] += pg * b3.z; o[15] += pg * b3.w;
    }

    uint4 r0, r1;
    r0.x = pack_bf16x2(o[0],  o[1]);  r0.y = pack_bf16x2(o[2],  o[3]);
    r0.z = pack_bf16x2(o[4],  o[5]);  r0.w = pack_bf16x2(o[6],  o[7]);
    r1.x = pack_bf16x2(o[8],  o[9]);  r1.y = pack_bf16x2(o[10], o[11]);
    r1.z = pack_bf16x2(o[12], o[13]); r1.w = pack_bf16x2(o[14], o[15]);
    unsigned short* ob = outb + (size_t)tok * DIM + h * 64 + p * 16;
    *(uint4*)(ob)     = r0;
    *(uint4*)(ob + 8) = r1;
}

// ---------------- launch ----------------
extern "C" void kernel_launch(void* const* d_in, const int* in_sizes, int n_in,
                              void* d_out, int out_size, void* d_ws, size_t ws_size,
                              hipStream_t stream) {
    const float* x      = (const float*)d_in[0];   // 16384 x 1024
    const float* fcos   = (const float*)d_in[1];   // 4096 x 32
    const float* fsin   = (const float*)d_in[2];
    const float* w_qkv  = (const float*)d_in[3];   // 1024 x 3072
    const float* g_q    = (const float*)d_in[4];
    const float* g_k    = (const float*)d_in[5];
    const float* w_proj = (const float*)d_in[6];   // 1024 x 1024
    const float* b_proj = (const float*)d_in[7];
    float* out = (float*)d_out;

    char* ws = (char*)d_ws;
    // workspace layout (bytes)
    unsigned short* xb      = (unsigned short*)(ws);                       // 33,554,432
    unsigned short* wqkvT   = (unsigned short*)(ws + 33554432);            //  6,291,456
    unsigned short* wprojT  = (unsigned short*)(ws + 39845888);            //  2,097,152
    unsigned short* qkv     = (unsigned short*)(ws + 41943040);            // 100,663,296
    unsigned short* attnout = (unsigned short*)(ws + 142606336);           // 33,554,432
    (void)ws_size; (void)in_sizes; (void)n_in; (void)out_size;

    // 1. casts / transposes
    {
        int n4 = (NTOK * DIM) / 4;   // 4,194,304
        cvt_f32_bf16<<<(n4 + 255) / 256, 256, 0, stream>>>(
            (const float4*)x, (ushort4*)xb, n4);
        transpose_cvt<<<dim3(K3 / 32, DIM / 32), dim3(32, 8), 0, stream>>>(
            w_qkv, wqkvT, DIM, K3);
        transpose_cvt<<<dim3(DIM / 32, DIM / 32), dim3(32, 8), 0, stream>>>(
            w_proj, wprojT, DIM, DIM);
    }
    // 2. qkv = x @ w_qkv   (bf16 out)
    gemm_bf16_128<0><<<dim3(K3 / 128, NTOK / 128), 256, 0, stream>>>(
        xb, wqkvT, (void*)qkv, nullptr, NTOK, K3, DIM);
    // 3. per-token attention (wave per token, 4 tokens/block)
    attn_tok<<<NTOK / 4, 256, 0, stream>>>(qkv, fcos, fsin, g_q, g_k, attnout);
    // 4. out = attn @ w_proj + b   (fp32 out)
    gemm_bf16_128<1><<<dim3(DIM / 128, NTOK / 128), 256, 0, stream>>>(
        attnout, wprojT, (void*)out, b_proj, NTOK, DIM, DIM);
}